// Round 1
// 119.232 us; speedup vs baseline: 1.0169x; 1.0169x over previous
//
#include <hip/hip_runtime.h>
#include <hip/hip_bf16.h>
#include <math.h>

// Shapes: x(8,64,128,128) f32; wt(4,4,64,64,3,3) f32; attn_w(4,64); attn_b(4)
// Subband space: 64x64, 4 subbands, 64 cin, 64 cout.
// feats layout: [b][sub][66][66][64c] bf16, zero border ring (pad=1).

typedef __bf16 bf16x8 __attribute__((ext_vector_type(8)));
typedef float f32x4 __attribute__((ext_vector_type(4)));

__device__ __forceinline__ bf16x8 as_bf16x8(uint4 u) {
    union { uint4 a; bf16x8 b; } c; c.a = u; return c.b;
}
__device__ __forceinline__ unsigned short bf16bits(float f) {
    __hip_bfloat16 h = __float2bfloat16(f);
    union { __hip_bfloat16 h; unsigned short u; } c; c.h = h; return c.u;
}
// async 16B global -> LDS (DMA; LDS dest = wave-uniform base + lane*16)
__device__ __forceinline__ void gload_lds16(const uint4* g, uint4* l) {
    __builtin_amdgcn_global_load_lds(
        (const __attribute__((address_space(1))) unsigned int*)g,
        (__attribute__((address_space(3))) unsigned int*)l, 16, 0, 0);
}

#define FPLANE 34848   // 66*66*8 uint4 per (b,sub) plane
#define FROW   528     // 66*8

// ---------------------------------------------------------------------------
// K1: Haar DWT -> bf16 feats (padded, zero ring) + per-y partial logits
// grid (64 y, 8 b), 256 threads.  (unchanged)
// ---------------------------------------------------------------------------
__global__ __launch_bounds__(256)
void dwt_kernel(const float* __restrict__ x, const float* __restrict__ attn_w,
                unsigned short* __restrict__ feats, float* __restrict__ plog) {
    __shared__ uint4 sT[2304];                     // 4 sub * 64 x * 9 chunks (72 bf16)
    __shared__ float sred[64][4];                  // [c][sub]
    unsigned short* sTu = (unsigned short*)sT;
    int y = blockIdx.x, b = blockIdx.y;
    int t = threadIdx.x;
    int c = t >> 2, q = t & 3;

    const float4* r0 = (const float4*)x + ((size_t)(b * 64 + c) * 128 + 2 * y) * 32;
    const float4* r1 = r0 + 32;

    float s0 = 0.f, s1 = 0.f, s2 = 0.f, s3 = 0.f;
    #pragma unroll
    for (int i = 0; i < 8; ++i) {
        int f = i * 4 + q;                         // quad covers 64B contiguous
        float4 p = r0[f], qq = r1[f];
        int xo = 2 * f;
        {
            float a = p.x, bb = p.y, cc = qq.x, dd = qq.y;
            float ll = (a + bb + cc + dd) * 0.5f, h0 = (a + bb - cc - dd) * 0.5f;
            float h1 = (a - bb + cc - dd) * 0.5f, hh = (a - bb - cc + dd) * 0.5f;
            s0 += ll; s1 += h0; s2 += h1; s3 += hh;
            sTu[0 * 4608 + xo * 72 + c] = bf16bits(ll);
            sTu[1 * 4608 + xo * 72 + c] = bf16bits(h0);
            sTu[2 * 4608 + xo * 72 + c] = bf16bits(h1);
            sTu[3 * 4608 + xo * 72 + c] = bf16bits(hh);
        }
        {
            float a = p.z, bb = p.w, cc = qq.z, dd = qq.w;
            float ll = (a + bb + cc + dd) * 0.5f, h0 = (a + bb - cc - dd) * 0.5f;
            float h1 = (a - bb + cc - dd) * 0.5f, hh = (a - bb - cc + dd) * 0.5f;
            s0 += ll; s1 += h0; s2 += h1; s3 += hh;
            sTu[0 * 4608 + (xo + 1) * 72 + c] = bf16bits(ll);
            sTu[1 * 4608 + (xo + 1) * 72 + c] = bf16bits(h0);
            sTu[2 * 4608 + (xo + 1) * 72 + c] = bf16bits(h1);
            sTu[3 * 4608 + (xo + 1) * 72 + c] = bf16bits(hh);
        }
    }
    s0 += __shfl_xor(s0, 1); s0 += __shfl_xor(s0, 2);
    s1 += __shfl_xor(s1, 1); s1 += __shfl_xor(s1, 2);
    s2 += __shfl_xor(s2, 1); s2 += __shfl_xor(s2, 2);
    s3 += __shfl_xor(s3, 1); s3 += __shfl_xor(s3, 2);
    if (q == 0) { sred[c][0] = s0; sred[c][1] = s1; sred[c][2] = s2; sred[c][3] = s3; }
    __syncthreads();
    if (t < 16) {
        int sub = t >> 2, k = t & 3;
        float acc = 0.f;
        #pragma unroll 8
        for (int cc = 0; cc < 64; ++cc)
            acc += attn_w[k * 64 + cc] * sred[cc][sub];
        plog[((size_t)(b * 4 + sub) * 4 + k) * 64 + y] = acc;
    }
    // padded channel-last writes: row y+1 of each plane, zero side borders
    uint4* fpad = (uint4*)feats;
    const uint4 zz = make_uint4(0u, 0u, 0u, 0u);
    for (int e = t; e < 2112; e += 256) {
        int s = e / 528, r = e - s * 528;
        int px = r >> 3, ck = r & 7;
        uint4 v = zz;
        if (px >= 1 && px <= 64) v = sT[s * 576 + (px - 1) * 9 + ck];
        fpad[((size_t)(b * 4 + s) * 66 + (y + 1)) * FROW + r] = v;
    }
    if (y == 0) {
        for (int e = t; e < 2112; e += 256) {
            int s = e / 528, r = e - s * 528;
            fpad[(size_t)(b * 4 + s) * 66 * FROW + r] = zz;
        }
    } else if (y == 63) {
        for (int e = t; e < 2112; e += 256) {
            int s = e / 528, r = e - s * 528;
            fpad[((size_t)(b * 4 + s) * 66 + 65) * FROW + r] = zz;
        }
    }
}

// ---------------------------------------------------------------------------
// K2: attention (from plog) + kernel mixing -> bf16 wmix[b][sub][tap][co][ci]
// grid (64 co, 4 sub), 256 threads.  (unchanged)
// ---------------------------------------------------------------------------
__global__ __launch_bounds__(256)
void mix_kernel(const float* __restrict__ wt, const float* __restrict__ attn_b,
                const float* __restrict__ plog, unsigned short* __restrict__ wmix) {
    __shared__ float sLw[4][576];       // [k][ci*9+tap]
    __shared__ float satt[8][4];        // [b][k]
    int co = blockIdx.x, sub = blockIdx.y;
    int t = threadIdx.x;

    if (t < 32) {
        int b = t >> 2, k = t & 3;
        const float* pp = plog + ((size_t)(b * 4 + sub) * 4 + k) * 64;
        float acc = 0.f;
        #pragma unroll 8
        for (int yy = 0; yy < 64; ++yy) acc += pp[yy];
        float logit = acc * (1.0f / 4096.0f) + attn_b[k];
        float m = fmaxf(logit, __shfl_xor(logit, 1));
        m = fmaxf(m, __shfl_xor(m, 2));
        float e = expf(logit - m);
        float s = e + __shfl_xor(e, 1);
        s += __shfl_xor(s, 2);
        satt[b][k] = e / s;
    }
    for (int e = t; e < 2304; e += 256) {
        int k = e / 576, r = e - k * 576;
        sLw[k][r] = wt[((size_t)(k * 4 + sub) * 64 + co) * 576 + r];
    }
    __syncthreads();
    #pragma unroll
    for (int j = 0; j < 18; ++j) {
        int idx = j * 256 + t;
        int b = idx / 576;
        int r = idx - b * 576;
        int tap = r >> 6, ci = r & 63;
        int wi = ci * 9 + tap;
        float v = satt[b][0] * sLw[0][wi] + satt[b][1] * sLw[1][wi]
                + satt[b][2] * sLw[2][wi] + satt[b][3] * sLw[3][wi];
        wmix[((size_t)(b * 4 + sub) * 9 + tap) * 4096 + co * 64 + ci] = bf16bits(v);
    }
}

// ---------------------------------------------------------------------------
// K3': fused conv + Haar IDWT.
// One block = one 16x16 subband-space tile x 32 couts x ALL 4 subbands.
// Signs of the IDWT are folded into 4 per-quad f32 accumulators; the final
// 32x32 output tile is written directly as f32 (conv_out eliminated).
// grid (16 tiles * 2 cg, 8 b) = 256 blocks, 512 threads (8 waves).
// Wave w: py rows (w>>1)*4 .. +3, co half (w&1)*16.
// Double-buffered LDS (78.3 KB), 2-phase prefetch: issue phase p+1 loads
// before computing phase p; single __syncthreads (with vmcnt drain) per phase.
// 8 phases: (sub 0..3) x (ci-chunk 0..1).
// ---------------------------------------------------------------------------
__device__ __forceinline__ void stage_phase(const uint4* __restrict__ fp,
                                            const uint4* __restrict__ wch,
                                            uint4* sAb, uint4* sWb,
                                            int y0, int x0, int cg, int ck8, int t) {
    // A halo: 18x18 px * 4 g-chunks (32 ci) = 1296 uint4
    #pragma unroll
    for (int i = 0; i < 2; ++i) {
        int e = t + i * 512;
        int py = e / 72, rr = e - py * 72, px = rr >> 2, g = rr & 3;
        gload_lds16(fp + (size_t)((y0 + py) * 66 + x0 + px) * 8 + ck8 + g, &sAb[e]);
    }
    if (t < 256) {                                  // waves 0-3: wave-uniform
        int e = 1024 + t;
        int py = e / 72, rr = e - py * 72, px = rr >> 2, g = rr & 3;
        gload_lds16(fp + (size_t)((y0 + py) * 66 + x0 + px) * 8 + ck8 + g, &sAb[e]);
    }
    if (t < 16) {                                   // tail: direct load+store
        int e = 1280 + t;
        int rr = e - 1224, px = rr >> 2, g = rr & 3;   // py = 17
        sAb[e] = fp[(size_t)((y0 + 17) * 66 + x0 + px) * 8 + ck8 + g];
    }
    // W: 9 taps x 32 co (this cg half) x 32 ci = 1152 uint4
    #pragma unroll
    for (int i = 0; i < 2; ++i) {
        int e = t + i * 512;
        int tap = e >> 7, rr = e & 127, co = rr >> 2, g = rr & 3;
        gload_lds16(wch + tap * 512 + (cg * 32 + co) * 8 + ck8 + g, &sWb[e]);
    }
    if (t < 128) {                                  // waves 0,1: wave-uniform
        int e = 1024 + t;
        int tap = e >> 7, rr = e & 127, co = rr >> 2, g = rr & 3;
        gload_lds16(wch + tap * 512 + (cg * 32 + co) * 8 + ck8 + g, &sWb[e]);
    }
}

__global__ __launch_bounds__(512)
void conv_idwt_kernel(const unsigned short* __restrict__ feats,
                      const unsigned short* __restrict__ wmix,
                      float* __restrict__ out) {
    __shared__ uint4 sA[2][1296];      // double-buffered A halo
    __shared__ uint4 sW[2][1152];      // double-buffered weights
    int bx = blockIdx.x;
    int tile = bx & 15, cg = bx >> 4;
    int b = blockIdx.y;
    int y0 = (tile >> 2) * 16, x0 = (tile & 3) * 16;
    int t = threadIdx.x, w = t >> 6, l = t & 63;
    int l16 = l & 15, kg = l >> 4;
    int wy4 = (w >> 1) * 4, wn = w & 1;

    const uint4* fpb = (const uint4*)feats + (size_t)b * 4 * FPLANE;
    const uint4* wcb = (const uint4*)wmix + (size_t)b * 4 * 4608;

    f32x4 accQ[4][4];                  // [quad a,b,c,d][r]
    f32x4 accS[4];                     // current-subband conv accumulator
    #pragma unroll
    for (int qd = 0; qd < 4; ++qd)
        #pragma unroll
        for (int r = 0; r < 4; ++r)
            accQ[qd][r] = (f32x4){0.f, 0.f, 0.f, 0.f};
    #pragma unroll
    for (int r = 0; r < 4; ++r) accS[r] = (f32x4){0.f, 0.f, 0.f, 0.f};

    // prologue: stage phase 0 (sub 0, chunk 0)
    stage_phase(fpb, wcb, sA[0], sW[0], y0, x0, cg, 0, t);
    __syncthreads();

    #pragma unroll
    for (int p = 0; p < 8; ++p) {
        const int sub = p >> 1;
        // issue next phase's loads first -- they land during the MFMA stretch
        if (p < 7) {
            const int ns = (p + 1) >> 1, nc = ((p + 1) & 1) * 4;
            stage_phase(fpb + (size_t)ns * FPLANE, wcb + (size_t)ns * 4608,
                        sA[(p + 1) & 1], sW[(p + 1) & 1], y0, x0, cg, nc, t);
        }
        // compute current phase from buffer p&1
        {
            const uint4* A = sA[p & 1];
            const uint4* W = sW[p & 1];
            uint4 af[4][3];
            #pragma unroll
            for (int i = 0; i < 4; ++i)
                #pragma unroll
                for (int dx = 0; dx < 3; ++dx)
                    af[i][dx] = A[((wy4 + i) * 18 + l16 + dx) * 4 + kg];
            #pragma unroll
            for (int dy = 0; dy < 3; ++dy) {
                if (dy > 0) {
                    #pragma unroll
                    for (int i = 0; i < 3; ++i)
                        #pragma unroll
                        for (int dx = 0; dx < 3; ++dx)
                            af[i][dx] = af[i + 1][dx];
                    #pragma unroll
                    for (int dx = 0; dx < 3; ++dx)
                        af[3][dx] = A[((wy4 + dy + 3) * 18 + l16 + dx) * 4 + kg];
                }
                #pragma unroll
                for (int dx = 0; dx < 3; ++dx) {
                    int tap = dy * 3 + dx;
                    bf16x8 bw = as_bf16x8(W[tap * 128 + (wn * 16 + l16) * 4 + kg]);
                    #pragma unroll
                    for (int r = 0; r < 4; ++r)
                        accS[r] = __builtin_amdgcn_mfma_f32_16x16x32_bf16(
                            as_bf16x8(af[r][dx]), bw, accS[r], 0, 0, 0);
                }
            }
        }
        // end of subband: fold into quad accumulators with IDWT signs
        // a: + + + +   b: + + - -   c: + - + -   d: + - - +   (over ll,h0,h1,hh)
        if (p & 1) {
            const float g1 = (sub <= 1) ? 1.f : -1.f;
            const float g2 = (sub == 0 || sub == 2) ? 1.f : -1.f;
            const float g3 = (sub == 0 || sub == 3) ? 1.f : -1.f;
            #pragma unroll
            for (int r = 0; r < 4; ++r) {
                #pragma unroll
                for (int j = 0; j < 4; ++j) {
                    float v = accS[r][j];
                    accQ[0][r][j] += v;
                    accQ[1][r][j] += g1 * v;
                    accQ[2][r][j] += g2 * v;
                    accQ[3][r][j] += g3 * v;
                    accS[r][j] = 0.f;
                }
            }
        }
        __syncthreads();
    }

    // epilogue: D row=(lane>>4)*4+reg = x offset, col=lane&15 = co (within 16)
    // subband pixel (y,x) -> out rows 2y (a,b interleaved), 2y+1 (c,d)
    #pragma unroll
    for (int r = 0; r < 4; ++r) {
        int y = y0 + wy4 + r;
        int co = cg * 32 + wn * 16 + l16;
        float* otop = out + ((size_t)(b * 64 + co) * 128 + 2 * y) * 128
                          + 2 * (x0 + kg * 4);
        float* obot = otop + 128;
        #pragma unroll
        for (int jp = 0; jp < 2; ++jp) {
            float4 vt, vb;
            vt.x = 0.5f * accQ[0][r][2 * jp];
            vt.y = 0.5f * accQ[1][r][2 * jp];
            vt.z = 0.5f * accQ[0][r][2 * jp + 1];
            vt.w = 0.5f * accQ[1][r][2 * jp + 1];
            vb.x = 0.5f * accQ[2][r][2 * jp];
            vb.y = 0.5f * accQ[3][r][2 * jp];
            vb.z = 0.5f * accQ[2][r][2 * jp + 1];
            vb.w = 0.5f * accQ[3][r][2 * jp + 1];
            *(float4*)(otop + 4 * jp) = vt;
            *(float4*)(obot + 4 * jp) = vb;
        }
    }
}

// ---------------------------------------------------------------------------
extern "C" void kernel_launch(void* const* d_in, const int* in_sizes, int n_in,
                              void* d_out, int out_size, void* d_ws, size_t ws_size,
                              hipStream_t stream) {
    const float* x  = (const float*)d_in[0];
    const float* wt = (const float*)d_in[1];
    const float* aw = (const float*)d_in[2];
    const float* ab = (const float*)d_in[3];
    float* out = (float*)d_out;
    char* ws = (char*)d_ws;

    float* plog           = (float*)ws;                              // 32,768 B
    unsigned short* feats = (unsigned short*)(ws + 32768);           // 17,842,176 B (padded)
    unsigned short* wmix  = (unsigned short*)(ws + 32768 + 17842176);// 2,359,296 B

    hipLaunchKernelGGL(dwt_kernel, dim3(64, 8), dim3(256), 0, stream, x, aw, feats, plog);
    hipLaunchKernelGGL(mix_kernel, dim3(64, 4), dim3(256), 0, stream, wt, ab, plog, wmix);
    hipLaunchKernelGGL(conv_idwt_kernel, dim3(32, 8), dim3(512), 0, stream,
                       feats, wmix, out);
}

// Round 2
// 116.971 us; speedup vs baseline: 1.0366x; 1.0193x over previous
//
#include <hip/hip_runtime.h>
#include <hip/hip_bf16.h>
#include <math.h>

// Shapes: x(8,64,128,128) f32; wt(4,4,64,64,3,3) f32; attn_w(4,64); attn_b(4)
// Subband space: 64x64, 4 subbands, 64 cin, 64 cout.
// feats layout: [b][sub][66][66][64c] bf16, zero border ring (pad=1).

typedef __bf16 bf16x8 __attribute__((ext_vector_type(8)));
typedef float f32x4 __attribute__((ext_vector_type(4)));

__device__ __forceinline__ bf16x8 as_bf16x8(uint4 u) {
    union { uint4 a; bf16x8 b; } c; c.a = u; return c.b;
}
__device__ __forceinline__ unsigned short bf16bits(float f) {
    __hip_bfloat16 h = __float2bfloat16(f);
    union { __hip_bfloat16 h; unsigned short u; } c; c.h = h; return c.u;
}
// async 16B global -> LDS (DMA; LDS dest = wave-uniform base + lane*16)
__device__ __forceinline__ void gload_lds16(const uint4* g, uint4* l) {
    __builtin_amdgcn_global_load_lds(
        (const __attribute__((address_space(1))) unsigned int*)g,
        (__attribute__((address_space(3))) unsigned int*)l, 16, 0, 0);
}

#define FPLANE 34848   // 66*66*8 uint4 per (b,sub) plane
#define FROW   528     // 66*8

// ---------------------------------------------------------------------------
// K1: Haar DWT -> bf16 feats (padded, zero ring) + per-y partial logits
// grid (64 y, 8 b), 256 threads.  (unchanged)
// ---------------------------------------------------------------------------
__global__ __launch_bounds__(256)
void dwt_kernel(const float* __restrict__ x, const float* __restrict__ attn_w,
                unsigned short* __restrict__ feats, float* __restrict__ plog) {
    __shared__ uint4 sT[2304];                     // 4 sub * 64 x * 9 chunks (72 bf16)
    __shared__ float sred[64][4];                  // [c][sub]
    unsigned short* sTu = (unsigned short*)sT;
    int y = blockIdx.x, b = blockIdx.y;
    int t = threadIdx.x;
    int c = t >> 2, q = t & 3;

    const float4* r0 = (const float4*)x + ((size_t)(b * 64 + c) * 128 + 2 * y) * 32;
    const float4* r1 = r0 + 32;

    float s0 = 0.f, s1 = 0.f, s2 = 0.f, s3 = 0.f;
    #pragma unroll
    for (int i = 0; i < 8; ++i) {
        int f = i * 4 + q;                         // quad covers 64B contiguous
        float4 p = r0[f], qq = r1[f];
        int xo = 2 * f;
        {
            float a = p.x, bb = p.y, cc = qq.x, dd = qq.y;
            float ll = (a + bb + cc + dd) * 0.5f, h0 = (a + bb - cc - dd) * 0.5f;
            float h1 = (a - bb + cc - dd) * 0.5f, hh = (a - bb - cc + dd) * 0.5f;
            s0 += ll; s1 += h0; s2 += h1; s3 += hh;
            sTu[0 * 4608 + xo * 72 + c] = bf16bits(ll);
            sTu[1 * 4608 + xo * 72 + c] = bf16bits(h0);
            sTu[2 * 4608 + xo * 72 + c] = bf16bits(h1);
            sTu[3 * 4608 + xo * 72 + c] = bf16bits(hh);
        }
        {
            float a = p.z, bb = p.w, cc = qq.z, dd = qq.w;
            float ll = (a + bb + cc + dd) * 0.5f, h0 = (a + bb - cc - dd) * 0.5f;
            float h1 = (a - bb + cc - dd) * 0.5f, hh = (a - bb - cc + dd) * 0.5f;
            s0 += ll; s1 += h0; s2 += h1; s3 += hh;
            sTu[0 * 4608 + (xo + 1) * 72 + c] = bf16bits(ll);
            sTu[1 * 4608 + (xo + 1) * 72 + c] = bf16bits(h0);
            sTu[2 * 4608 + (xo + 1) * 72 + c] = bf16bits(h1);
            sTu[3 * 4608 + (xo + 1) * 72 + c] = bf16bits(hh);
        }
    }
    s0 += __shfl_xor(s0, 1); s0 += __shfl_xor(s0, 2);
    s1 += __shfl_xor(s1, 1); s1 += __shfl_xor(s1, 2);
    s2 += __shfl_xor(s2, 1); s2 += __shfl_xor(s2, 2);
    s3 += __shfl_xor(s3, 1); s3 += __shfl_xor(s3, 2);
    if (q == 0) { sred[c][0] = s0; sred[c][1] = s1; sred[c][2] = s2; sred[c][3] = s3; }
    __syncthreads();
    if (t < 16) {
        int sub = t >> 2, k = t & 3;
        float acc = 0.f;
        #pragma unroll 8
        for (int cc = 0; cc < 64; ++cc)
            acc += attn_w[k * 64 + cc] * sred[cc][sub];
        plog[((size_t)(b * 4 + sub) * 4 + k) * 64 + y] = acc;
    }
    // padded channel-last writes: row y+1 of each plane, zero side borders
    uint4* fpad = (uint4*)feats;
    const uint4 zz = make_uint4(0u, 0u, 0u, 0u);
    for (int e = t; e < 2112; e += 256) {
        int s = e / 528, r = e - s * 528;
        int px = r >> 3, ck = r & 7;
        uint4 v = zz;
        if (px >= 1 && px <= 64) v = sT[s * 576 + (px - 1) * 9 + ck];
        fpad[((size_t)(b * 4 + s) * 66 + (y + 1)) * FROW + r] = v;
    }
    if (y == 0) {
        for (int e = t; e < 2112; e += 256) {
            int s = e / 528, r = e - s * 528;
            fpad[(size_t)(b * 4 + s) * 66 * FROW + r] = zz;
        }
    } else if (y == 63) {
        for (int e = t; e < 2112; e += 256) {
            int s = e / 528, r = e - s * 528;
            fpad[((size_t)(b * 4 + s) * 66 + 65) * FROW + r] = zz;
        }
    }
}

// ---------------------------------------------------------------------------
// K2: attention (from plog) + kernel mixing -> bf16 wmix[b][sub][tap][co][ci]
// grid (64 co, 4 sub), 256 threads.  (unchanged)
// ---------------------------------------------------------------------------
__global__ __launch_bounds__(256)
void mix_kernel(const float* __restrict__ wt, const float* __restrict__ attn_b,
                const float* __restrict__ plog, unsigned short* __restrict__ wmix) {
    __shared__ float sLw[4][576];       // [k][ci*9+tap]
    __shared__ float satt[8][4];        // [b][k]
    int co = blockIdx.x, sub = blockIdx.y;
    int t = threadIdx.x;

    if (t < 32) {
        int b = t >> 2, k = t & 3;
        const float* pp = plog + ((size_t)(b * 4 + sub) * 4 + k) * 64;
        float acc = 0.f;
        #pragma unroll 8
        for (int yy = 0; yy < 64; ++yy) acc += pp[yy];
        float logit = acc * (1.0f / 4096.0f) + attn_b[k];
        float m = fmaxf(logit, __shfl_xor(logit, 1));
        m = fmaxf(m, __shfl_xor(m, 2));
        float e = expf(logit - m);
        float s = e + __shfl_xor(e, 1);
        s += __shfl_xor(s, 2);
        satt[b][k] = e / s;
    }
    for (int e = t; e < 2304; e += 256) {
        int k = e / 576, r = e - k * 576;
        sLw[k][r] = wt[((size_t)(k * 4 + sub) * 64 + co) * 576 + r];
    }
    __syncthreads();
    #pragma unroll
    for (int j = 0; j < 18; ++j) {
        int idx = j * 256 + t;
        int b = idx / 576;
        int r = idx - b * 576;
        int tap = r >> 6, ci = r & 63;
        int wi = ci * 9 + tap;
        float v = satt[b][0] * sLw[0][wi] + satt[b][1] * sLw[1][wi]
                + satt[b][2] * sLw[2][wi] + satt[b][3] * sLw[3][wi];
        wmix[((size_t)(b * 4 + sub) * 9 + tap) * 4096 + co * 64 + ci] = bf16bits(v);
    }
}

// ---------------------------------------------------------------------------
// K3': fused conv + Haar IDWT, 8x16 tiles for 2 blocks/CU.
// One block = one 8x16 subband-space tile x 32 couts x ALL 4 subbands.
// grid 512 blocks (1-D; b = lin&7 so each XCD owns one batch -> feats+wmix
// L2-resident per XCD), 256 threads (4 waves = 2 y-groups x 2 co-halves).
// Double-buffered LDS 61.4 KB -> 2 blocks/CU; 2-phase prefetch: issue phase
// p+1 loads before computing phase p; one __syncthreads per phase.
// 8 phases: (sub 0..3) x (ci-chunk 0..1).  IDWT signs folded into accQ,
// final 16x32 f32 output tile written directly.
// ---------------------------------------------------------------------------
__device__ __forceinline__ void stage_phase(const uint4* __restrict__ fp,
                                            const uint4* __restrict__ wch,
                                            uint4* sAb, uint4* sWb,
                                            int y0, int x0, int cg, int ck8, int t) {
    // A halo: 10x18 px * 4 g-chunks (32 ci) = 720 uint4; padded to 768
    // (e 720..767 read row y0+10 -- garbage within allocated ws, never consumed)
    #pragma unroll
    for (int i = 0; i < 3; ++i) {
        int e = t + i * 256;
        int py = e / 72, rr = e - py * 72, px = rr >> 2, g = rr & 3;
        gload_lds16(fp + (size_t)((y0 + py) * 66 + x0 + px) * 8 + ck8 + g, &sAb[e]);
    }
    // W: 9 taps x 32 co (this cg half) x 32 ci = 1152 uint4
    #pragma unroll
    for (int i = 0; i < 4; ++i) {
        int e = t + i * 256;
        int tap = e >> 7, rr = e & 127, co = rr >> 2, g = rr & 3;
        gload_lds16(wch + tap * 512 + (cg * 32 + co) * 8 + ck8 + g, &sWb[e]);
    }
    if (t < 128) {                                  // tail: waves 0,1 (wave-uniform)
        int e = 1024 + t;
        int tap = e >> 7, rr = e & 127, co = rr >> 2, g = rr & 3;
        gload_lds16(wch + tap * 512 + (cg * 32 + co) * 8 + ck8 + g, &sWb[e]);
    }
}

__global__ __launch_bounds__(256, 2)
void conv_idwt_kernel(const unsigned short* __restrict__ feats,
                      const unsigned short* __restrict__ wmix,
                      float* __restrict__ out) {
    __shared__ uint4 sA[2][768];       // double-buffered A halo (10x18x4 + pad)
    __shared__ uint4 sW[2][1152];      // double-buffered weights
    int lin = blockIdx.x;
    int b = lin & 7;                   // XCD-chunked: XCD k -> batch k
    int rest = lin >> 3;               // [0,64)
    int cg = rest >> 5, tile = rest & 31;
    int y0 = (tile >> 2) * 8, x0 = (tile & 3) * 16;
    int t = threadIdx.x, w = t >> 6, l = t & 63;
    int l16 = l & 15, kg = l >> 4;
    int wy4 = (w >> 1) * 4, wn = w & 1;

    const uint4* fpb = (const uint4*)feats + (size_t)b * 4 * FPLANE;
    const uint4* wcb = (const uint4*)wmix + (size_t)b * 4 * 4608;

    f32x4 accQ[4][4];                  // [quad a,b,c,d][r]
    f32x4 accS[4];                     // current-subband conv accumulator
    #pragma unroll
    for (int qd = 0; qd < 4; ++qd)
        #pragma unroll
        for (int r = 0; r < 4; ++r)
            accQ[qd][r] = (f32x4){0.f, 0.f, 0.f, 0.f};
    #pragma unroll
    for (int r = 0; r < 4; ++r) accS[r] = (f32x4){0.f, 0.f, 0.f, 0.f};

    // prologue: stage phase 0 (sub 0, chunk 0)
    stage_phase(fpb, wcb, sA[0], sW[0], y0, x0, cg, 0, t);
    __syncthreads();

    #pragma unroll
    for (int p = 0; p < 8; ++p) {
        const int sub = p >> 1;
        // issue next phase's loads first -- they land during the MFMA stretch
        if (p < 7) {
            const int ns = (p + 1) >> 1, nc = ((p + 1) & 1) * 4;
            stage_phase(fpb + (size_t)ns * FPLANE, wcb + (size_t)ns * 4608,
                        sA[(p + 1) & 1], sW[(p + 1) & 1], y0, x0, cg, nc, t);
        }
        // compute current phase from buffer p&1
        {
            const uint4* A = sA[p & 1];
            const uint4* W = sW[p & 1];
            uint4 af[4][3];
            #pragma unroll
            for (int i = 0; i < 4; ++i)
                #pragma unroll
                for (int dx = 0; dx < 3; ++dx)
                    af[i][dx] = A[((wy4 + i) * 18 + l16 + dx) * 4 + kg];
            __builtin_amdgcn_s_setprio(1);
            #pragma unroll
            for (int dy = 0; dy < 3; ++dy) {
                if (dy > 0) {
                    #pragma unroll
                    for (int i = 0; i < 3; ++i)
                        #pragma unroll
                        for (int dx = 0; dx < 3; ++dx)
                            af[i][dx] = af[i + 1][dx];
                    #pragma unroll
                    for (int dx = 0; dx < 3; ++dx)
                        af[3][dx] = A[((wy4 + dy + 3) * 18 + l16 + dx) * 4 + kg];
                }
                #pragma unroll
                for (int dx = 0; dx < 3; ++dx) {
                    int tap = dy * 3 + dx;
                    bf16x8 bw = as_bf16x8(W[tap * 128 + (wn * 16 + l16) * 4 + kg]);
                    #pragma unroll
                    for (int r = 0; r < 4; ++r)
                        accS[r] = __builtin_amdgcn_mfma_f32_16x16x32_bf16(
                            as_bf16x8(af[r][dx]), bw, accS[r], 0, 0, 0);
                }
            }
            __builtin_amdgcn_s_setprio(0);
        }
        // end of subband: fold into quad accumulators with IDWT signs
        // a: + + + +   b: + + - -   c: + - + -   d: + - - +   (over ll,h0,h1,hh)
        if (p & 1) {
            const float g1 = (sub <= 1) ? 1.f : -1.f;
            const float g2 = (sub == 0 || sub == 2) ? 1.f : -1.f;
            const float g3 = (sub == 0 || sub == 3) ? 1.f : -1.f;
            #pragma unroll
            for (int r = 0; r < 4; ++r) {
                #pragma unroll
                for (int j = 0; j < 4; ++j) {
                    float v = accS[r][j];
                    accQ[0][r][j] += v;
                    accQ[1][r][j] += g1 * v;
                    accQ[2][r][j] += g2 * v;
                    accQ[3][r][j] += g3 * v;
                    accS[r][j] = 0.f;
                }
            }
        }
        __syncthreads();
    }

    // epilogue: D row=(lane>>4)*4+reg = x offset, col=lane&15 = co (within 16)
    // subband pixel (y,x) -> out rows 2y (a,b interleaved), 2y+1 (c,d)
    #pragma unroll
    for (int r = 0; r < 4; ++r) {
        int y = y0 + wy4 + r;
        int co = cg * 32 + wn * 16 + l16;
        float* otop = out + ((size_t)(b * 64 + co) * 128 + 2 * y) * 128
                          + 2 * (x0 + kg * 4);
        float* obot = otop + 128;
        #pragma unroll
        for (int jp = 0; jp < 2; ++jp) {
            float4 vt, vb;
            vt.x = 0.5f * accQ[0][r][2 * jp];
            vt.y = 0.5f * accQ[1][r][2 * jp];
            vt.z = 0.5f * accQ[0][r][2 * jp + 1];
            vt.w = 0.5f * accQ[1][r][2 * jp + 1];
            vb.x = 0.5f * accQ[2][r][2 * jp];
            vb.y = 0.5f * accQ[3][r][2 * jp];
            vb.z = 0.5f * accQ[2][r][2 * jp + 1];
            vb.w = 0.5f * accQ[3][r][2 * jp + 1];
            *(float4*)(otop + 4 * jp) = vt;
            *(float4*)(obot + 4 * jp) = vb;
        }
    }
}

// ---------------------------------------------------------------------------
extern "C" void kernel_launch(void* const* d_in, const int* in_sizes, int n_in,
                              void* d_out, int out_size, void* d_ws, size_t ws_size,
                              hipStream_t stream) {
    const float* x  = (const float*)d_in[0];
    const float* wt = (const float*)d_in[1];
    const float* aw = (const float*)d_in[2];
    const float* ab = (const float*)d_in[3];
    float* out = (float*)d_out;
    char* ws = (char*)d_ws;

    float* plog           = (float*)ws;                              // 32,768 B
    unsigned short* feats = (unsigned short*)(ws + 32768);           // 17,842,176 B (padded)
    unsigned short* wmix  = (unsigned short*)(ws + 32768 + 17842176);// 2,359,296 B

    hipLaunchKernelGGL(dwt_kernel, dim3(64, 8), dim3(256), 0, stream, x, aw, feats, plog);
    hipLaunchKernelGGL(mix_kernel, dim3(64, 4), dim3(256), 0, stream, wt, ab, plog, wmix);
    hipLaunchKernelGGL(conv_idwt_kernel, dim3(512), dim3(256), 0, stream,
                       feats, wmix, out);
}